// Round 17
// baseline (161.835 us; speedup 1.0000x reference)
//
#include <hip/hip_runtime.h>
#include <hip/hip_bf16.h>
#include <stdint.h>

#define B_ 4
#define C_ 256
#define N_ 4096
#define D_ 32

typedef __bf16 bf16_t;
typedef __bf16 bf16x8_t __attribute__((ext_vector_type(8)));
typedef float  f32x4    __attribute__((ext_vector_type(4)));

// ---------------------------------------------------------------------------
// cast W (wq|wk|wv) -> Wb bf16 [320][256]
// ---------------------------------------------------------------------------
__global__ __launch_bounds__(256) void cast_w_kernel(
    const float* __restrict__ wq, const float* __restrict__ wk,
    const float* __restrict__ wv, bf16_t* __restrict__ Wb)
{
  const int gr = blockIdx.x;
  const int t  = threadIdx.x;
  float v;
  if (gr < 32)      v = wq[gr * C_ + t];
  else if (gr < 64) v = wk[(gr - 32) * C_ + t];
  else              v = wv[(gr - 64) * C_ + t];
  Wb[gr * C_ + t] = (bf16_t)v;
}

// ---------------------------------------------------------------------------
// Projection GEMM with fused x-transpose (R12/R15 proven version).
// ---------------------------------------------------------------------------
__global__ __launch_bounds__(256) void proj_kernel(
    const float* __restrict__ x, const bf16_t* __restrict__ Wb,
    const float* __restrict__ bq, const float* __restrict__ bk,
    const float* __restrict__ bv,
    bf16_t* __restrict__ Qh, bf16_t* __restrict__ Kh, bf16_t* __restrict__ Vh)
{
  __shared__ float xs[64][65];
  const int bi = blockIdx.x;
  const int b  = bi & 3;
  const int n0 = (bi >> 2) * 64;
  const int t = threadIdx.x, w = t >> 6, lane = t & 63;
  const int l4 = lane >> 4, lm = lane & 15;

  const f32x4 z4 = {0.f, 0.f, 0.f, 0.f};
  f32x4 acc[5][4];
#pragma unroll
  for (int rt = 0; rt < 5; ++rt)
#pragma unroll
    for (int ct = 0; ct < 4; ++ct) acc[rt][ct] = z4;

  const int lr = t >> 2;
  const int lc = (t & 3) * 16;

#pragma unroll 1
  for (int k0 = 0; k0 < C_; k0 += 64) {
    __syncthreads();
#pragma unroll
    for (int i = 0; i < 4; ++i) {
      const f32x4 v = *(const f32x4*)(x + ((size_t)(b * C_ + k0 + lr)) * N_ + n0 + lc + i * 4);
      xs[lr][lc + i * 4 + 0] = v[0];
      xs[lr][lc + i * 4 + 1] = v[1];
      xs[lr][lc + i * 4 + 2] = v[2];
      xs[lr][lc + i * 4 + 3] = v[3];
    }
    __syncthreads();

    bf16x8_t af[5][2], bfr[4][2];
#pragma unroll
    for (int rt = 0; rt < 5; ++rt)
#pragma unroll
      for (int kc = 0; kc < 2; ++kc)
        af[rt][kc] = *(const bf16x8_t*)(Wb + (size_t)(w * 80 + rt * 16 + lm) * C_ + k0 + kc * 32 + l4 * 8);
#pragma unroll
    for (int ct = 0; ct < 4; ++ct)
#pragma unroll
      for (int kc = 0; kc < 2; ++kc) {
        bf16_t tmp[8];
#pragma unroll
        for (int j = 0; j < 8; ++j)
          tmp[j] = (bf16_t)xs[kc * 32 + l4 * 8 + j][ct * 16 + lm];
        bfr[ct][kc] = *(bf16x8_t*)tmp;
      }
#pragma unroll
    for (int rt = 0; rt < 5; ++rt)
#pragma unroll
      for (int ct = 0; ct < 4; ++ct)
#pragma unroll
        for (int kc = 0; kc < 2; ++kc)
          acc[rt][ct] = __builtin_amdgcn_mfma_f32_16x16x32_bf16(af[rt][kc], bfr[ct][kc], acc[rt][ct], 0, 0, 0);
  }

#pragma unroll
  for (int rt = 0; rt < 5; ++rt)
#pragma unroll
    for (int r = 0; r < 4; ++r) {
      const int gr = w * 80 + rt * 16 + 4 * l4 + r;
      const float bias = (gr < 32) ? bq[gr] : (gr < 64) ? bk[gr - 32] : bv[gr - 64];
#pragma unroll
      for (int ct = 0; ct < 4; ++ct) {
        const int n = n0 + ct * 16 + lm;
        float v = acc[rt][ct][r] + bias;
        if (gr < 32) {
          v *= 1.44269504088896f;
          Qh[((size_t)(b * N_ + n)) * D_ + gr] = (bf16_t)v;
        } else if (gr < 64) {
          Kh[((size_t)(b * N_ + n)) * D_ + (gr - 32)] = (bf16_t)v;
        } else {
          Vh[((size_t)(b * C_ + (gr - 64))) * N_ + n] = (bf16_t)v;
        }
      }
    }
}

// ---------------------------------------------------------------------------
// Flash attention, REGISTER-RESIDENT P (no P in LDS, ZERO main-loop barriers).
// Key insight: load K's A-fragment with permuted rows
//   row lm  <-  key  8*(lm>>2) + 4*mt + (lm&3)
// so S^T = mfma(K,Q) lands with lane (q=lm, g=l4) reg r = key 8g+4mt+r, i.e.
// exp2(S) concatenated over (mt=0 r0..3, mt=1 r0..3) IS the PV B-fragment
// (keys 8g..8g+7). P flows MFMA->exp2->cast->MFMA entirely in registers.
// 8 waves = 4 key-slices (ks) x 2 ch-halves (cp); wave owns 64 keys/tile
// (2 kg of 32), computes S for them (cp pair duplicates S: +20% MFMA),
// accumulates acc[128ch x 64q] partial over its keys. Fixed-reference exp2
// softmax; lane-local l. Epilogue: 2-round LDS combine over ks (128 KB Ax).
// ---------------------------------------------------------------------------
__global__ __launch_bounds__(512, 2) void attn_kernel(
    const bf16_t* __restrict__ Qh, const bf16_t* __restrict__ Kh,
    const bf16_t* __restrict__ Vh, const float* __restrict__ x,
    const float* __restrict__ gamma, float* __restrict__ out)
{
  __shared__ float Ax[4][256][2][16];   // 128 KB: [ks][ch][rt-low][q-lm]
  __shared__ float Lx[64][8];           // 2 KB:  [q][wave]

  const int bi = blockIdx.x;
  const int xcd = bi & 7, slot = bi >> 3;
  const int b  = xcd >> 1;                 // 2 XCDs per batch -> K,V,Q L2-resident
  const int q0 = ((xcd & 1) * 32 + slot) * 64;

  const int t = threadIdx.x, w = t >> 6, lane = t & 63;
  const int l4 = lane >> 4, lm = lane & 15;
  const int ks = w & 3, cp = w >> 2;

  const f32x4 z4 = {0.f, 0.f, 0.f, 0.f};

  // Q fragments (B-operand), held whole kernel
  bf16x8_t qf[4];
#pragma unroll
  for (int rt = 0; rt < 4; ++rt)
    qf[rt] = *(const bf16x8_t*)(Qh + ((size_t)(b * N_ + q0 + rt * 16 + lm)) * D_ + l4 * 8);

  // K base with PERMUTED rows: A-frag row lm covers key kperm + 4*mt
  const int kperm = 8 * (lm >> 2) + (lm & 3);
  const bf16_t* kbaseP = Kh + ((size_t)(b * N_ + ks * 64 + kperm)) * D_ + l4 * 8;
  // V base: this wave's 128 channels (cp half), its own key slice
  const bf16_t* vbase = Vh + ((size_t)(b * C_ + cp * 128 + lm)) * N_ + ks * 64 + 8 * l4;

  f32x4 acc[8][4];   // [ct][rt] : 128 ch x 64 q, partial over this wave's keys
#pragma unroll
  for (int ct = 0; ct < 8; ++ct)
#pragma unroll
    for (int rt = 0; rt < 4; ++rt) acc[ct][rt] = z4;
  float l_run[4] = {0.f, 0.f, 0.f, 0.f};

  // prologue: K fragments for (it=0, kg=0)
  bf16x8_t kf[2], kfn[2];
#pragma unroll
  for (int mt = 0; mt < 2; ++mt)
    kf[mt] = *(const bf16x8_t*)(kbaseP + (size_t)(4 * mt) * D_);

#pragma unroll 1
  for (int it = 0; it < N_ / 256; ++it) {
#pragma unroll
    for (int kg = 0; kg < 2; ++kg) {
      const int ko = it * 256 + kg * 32;   // wave-relative key offset

      // V fragments for this 32-key group (8 ct tiles x 16B/lane)
      bf16x8_t vf[8];
#pragma unroll
      for (int ct = 0; ct < 8; ++ct)
        vf[ct] = *(const bf16x8_t*)(vbase + (size_t)(ct * 16) * N_ + ko);

      // prefetch next kg's K fragments
      const int kon = (kg == 0) ? (ko + 32) : ((ko + 224) & (N_ - 1));
#pragma unroll
      for (int mt = 0; mt < 2; ++mt)
        kfn[mt] = *(const bf16x8_t*)(kbaseP + (size_t)(kon + 4 * mt) * D_);

      // S -> exp2 -> pack: per rt, p[] lands exactly in PV B-frag order
      bf16x8_t pb[4];
#pragma unroll
      for (int rt = 0; rt < 4; ++rt) {
        const f32x4 S0 = __builtin_amdgcn_mfma_f32_16x16x32_bf16(kf[0], qf[rt], z4, 0, 0, 0);
        const f32x4 S1 = __builtin_amdgcn_mfma_f32_16x16x32_bf16(kf[1], qf[rt], z4, 0, 0, 0);
        float p[8];
#pragma unroll
        for (int r = 0; r < 4; ++r) p[r]     = __builtin_amdgcn_exp2f(S0[r]);
#pragma unroll
        for (int r = 0; r < 4; ++r) p[4 + r] = __builtin_amdgcn_exp2f(S1[r]);
        l_run[rt] += ((p[0] + p[1]) + (p[2] + p[3])) + ((p[4] + p[5]) + (p[6] + p[7]));
        bf16_t tmp[8];
#pragma unroll
        for (int j = 0; j < 8; ++j) tmp[j] = (bf16_t)p[j];
        pb[rt] = *(bf16x8_t*)tmp;
      }

      // PV: 32 MFMAs, all operands in registers
#pragma unroll
      for (int ct = 0; ct < 8; ++ct)
#pragma unroll
        for (int rt = 0; rt < 4; ++rt)
          acc[ct][rt] = __builtin_amdgcn_mfma_f32_16x16x32_bf16(vf[ct], pb[rt], acc[ct][rt], 0, 0, 0);

      kf[0] = kfn[0];
      kf[1] = kfn[1];
    }
  }

  // ---- l reduce: lane-local -> per-q (shfl) -> Lx ----
#pragma unroll
  for (int rt = 0; rt < 4; ++rt) {
    l_run[rt] += __shfl_xor(l_run[rt], 16);
    l_run[rt] += __shfl_xor(l_run[rt], 32);
  }
  if (l4 == 0) {
#pragma unroll
    for (int rt = 0; rt < 4; ++rt) Lx[rt * 16 + lm][w] = l_run[rt];
  }

  // ---- 2-round combine over ks through Ax ----
  const float g = gamma[0];
#pragma unroll 1
  for (int p = 0; p < 2; ++p) {
    asm volatile("s_waitcnt lgkmcnt(0)" ::: "memory");
    __builtin_amdgcn_s_barrier();   // p=0: Lx visible; p=1: prev round's reads done

#pragma unroll
    for (int ct = 0; ct < 8; ++ct)
#pragma unroll
      for (int rtl = 0; rtl < 2; ++rtl)
#pragma unroll
        for (int r = 0; r < 4; ++r)
          Ax[ks][cp * 128 + ct * 16 + 4 * l4 + r][rtl][lm] = acc[ct][2 * p + rtl][r];

    asm volatile("s_waitcnt lgkmcnt(0)" ::: "memory");
    __builtin_amdgcn_s_barrier();

#pragma unroll
    for (int rtl = 0; rtl < 2; ++rtl) {
      const int ql = 32 * p + rtl * 16 + lm;
      const float lt = ((Lx[ql][0] + Lx[ql][1]) + (Lx[ql][2] + Lx[ql][3]));
      const float inv = 1.f / lt;
      const int n = q0 + ql;
#pragma unroll
      for (int c8 = 0; c8 < 8; ++c8) {
        const int ch = w * 32 + l4 * 8 + c8;
        const float s = (Ax[0][ch][rtl][lm] + Ax[1][ch][rtl][lm]) +
                        (Ax[2][ch][rtl][lm] + Ax[3][ch][rtl][lm]);
        const size_t idx = ((size_t)(b * C_ + ch)) * N_ + n;
        out[idx] = g * (s * inv) + x[idx];
      }
    }
  }
}

extern "C" void kernel_launch(void* const* d_in, const int* in_sizes, int n_in,
                              void* d_out, int out_size, void* d_ws, size_t ws_size,
                              hipStream_t stream) {
  const float* x     = (const float*)d_in[0];
  const float* wq    = (const float*)d_in[1];
  const float* bq    = (const float*)d_in[2];
  const float* wk    = (const float*)d_in[3];
  const float* bk    = (const float*)d_in[4];
  const float* wv    = (const float*)d_in[5];
  const float* bv    = (const float*)d_in[6];
  const float* gamma = (const float*)d_in[7];
  float* out = (float*)d_out;

  bf16_t* Qh = (bf16_t*)d_ws;
  bf16_t* Kh = Qh + (size_t)B_ * N_ * D_;
  bf16_t* Vh = Kh + (size_t)B_ * N_ * D_;
  bf16_t* Wb = Vh + (size_t)B_ * C_ * N_;

  cast_w_kernel<<<320, 256, 0, stream>>>(wq, wk, wv, Wb);
  proj_kernel<<<256, 256, 0, stream>>>(x, Wb, bq, bk, bv, Qh, Kh, Vh);
  attn_kernel<<<256, 512, 0, stream>>>(Qh, Kh, Vh, x, gamma, out);
}

// Round 18
// 103.769 us; speedup vs baseline: 1.5596x; 1.5596x over previous
//
#include <hip/hip_runtime.h>
#include <hip/hip_bf16.h>
#include <stdint.h>

#define B_ 4
#define C_ 256
#define N_ 4096
#define D_ 32

typedef __bf16 bf16_t;
typedef __bf16 bf16x8_t __attribute__((ext_vector_type(8)));
typedef float  f32x4    __attribute__((ext_vector_type(4)));

// ---------------------------------------------------------------------------
// cast W (wq|wk|wv) -> Wb bf16 [320][256]
// ---------------------------------------------------------------------------
__global__ __launch_bounds__(256) void cast_w_kernel(
    const float* __restrict__ wq, const float* __restrict__ wk,
    const float* __restrict__ wv, bf16_t* __restrict__ Wb)
{
  const int gr = blockIdx.x;
  const int t  = threadIdx.x;
  float v;
  if (gr < 32)      v = wq[gr * C_ + t];
  else if (gr < 64) v = wk[(gr - 32) * C_ + t];
  else              v = wv[(gr - 64) * C_ + t];
  Wb[gr * C_ + t] = (bf16_t)v;
}

// ---------------------------------------------------------------------------
// Projection GEMM with fused x-transpose (R12/R15 proven version).
// ---------------------------------------------------------------------------
__global__ __launch_bounds__(256) void proj_kernel(
    const float* __restrict__ x, const bf16_t* __restrict__ Wb,
    const float* __restrict__ bq, const float* __restrict__ bk,
    const float* __restrict__ bv,
    bf16_t* __restrict__ Qh, bf16_t* __restrict__ Kh, bf16_t* __restrict__ Vh)
{
  __shared__ float xs[64][65];
  const int bi = blockIdx.x;
  const int b  = bi & 3;
  const int n0 = (bi >> 2) * 64;
  const int t = threadIdx.x, w = t >> 6, lane = t & 63;
  const int l4 = lane >> 4, lm = lane & 15;

  const f32x4 z4 = {0.f, 0.f, 0.f, 0.f};
  f32x4 acc[5][4];
#pragma unroll
  for (int rt = 0; rt < 5; ++rt)
#pragma unroll
    for (int ct = 0; ct < 4; ++ct) acc[rt][ct] = z4;

  const int lr = t >> 2;
  const int lc = (t & 3) * 16;

#pragma unroll 1
  for (int k0 = 0; k0 < C_; k0 += 64) {
    __syncthreads();
#pragma unroll
    for (int i = 0; i < 4; ++i) {
      const f32x4 v = *(const f32x4*)(x + ((size_t)(b * C_ + k0 + lr)) * N_ + n0 + lc + i * 4);
      xs[lr][lc + i * 4 + 0] = v[0];
      xs[lr][lc + i * 4 + 1] = v[1];
      xs[lr][lc + i * 4 + 2] = v[2];
      xs[lr][lc + i * 4 + 3] = v[3];
    }
    __syncthreads();

    bf16x8_t af[5][2], bfr[4][2];
#pragma unroll
    for (int rt = 0; rt < 5; ++rt)
#pragma unroll
      for (int kc = 0; kc < 2; ++kc)
        af[rt][kc] = *(const bf16x8_t*)(Wb + (size_t)(w * 80 + rt * 16 + lm) * C_ + k0 + kc * 32 + l4 * 8);
#pragma unroll
    for (int ct = 0; ct < 4; ++ct)
#pragma unroll
      for (int kc = 0; kc < 2; ++kc) {
        bf16_t tmp[8];
#pragma unroll
        for (int j = 0; j < 8; ++j)
          tmp[j] = (bf16_t)xs[kc * 32 + l4 * 8 + j][ct * 16 + lm];
        bfr[ct][kc] = *(bf16x8_t*)tmp;
      }
#pragma unroll
    for (int rt = 0; rt < 5; ++rt)
#pragma unroll
      for (int ct = 0; ct < 4; ++ct)
#pragma unroll
        for (int kc = 0; kc < 2; ++kc)
          acc[rt][ct] = __builtin_amdgcn_mfma_f32_16x16x32_bf16(af[rt][kc], bfr[ct][kc], acc[rt][ct], 0, 0, 0);
  }

#pragma unroll
  for (int rt = 0; rt < 5; ++rt)
#pragma unroll
    for (int r = 0; r < 4; ++r) {
      const int gr = w * 80 + rt * 16 + 4 * l4 + r;
      const float bias = (gr < 32) ? bq[gr] : (gr < 64) ? bk[gr - 32] : bv[gr - 64];
#pragma unroll
      for (int ct = 0; ct < 4; ++ct) {
        const int n = n0 + ct * 16 + lm;
        float v = acc[rt][ct][r] + bias;
        if (gr < 32) {
          v *= 1.44269504088896f;
          Qh[((size_t)(b * N_ + n)) * D_ + gr] = (bf16_t)v;
        } else if (gr < 64) {
          Kh[((size_t)(b * N_ + n)) * D_ + (gr - 32)] = (bf16_t)v;
        } else {
          Vh[((size_t)(b * C_ + (gr - 64))) * N_ + n] = (bf16_t)v;
        }
      }
    }
}

// ---------------------------------------------------------------------------
// Flash attention, REGISTER-RESIDENT P, ZERO main-loop barriers, SPILL-FREE:
// 8 waves = 2 key-halves (ks: 2048 keys) x 4 ch-groups (cg: 64 ch).
// kperm trick (proven in R17): K A-frag row lm <- key 8*(lm>>2)+4*mt+(lm&3),
// so exp2(S) concatenated (mt0 r0..3, mt1 r0..3) IS the PV B-fragment in
// natural key order. P never touches LDS; waves fully independent.
// S/exp2 duplicated 4x across cg (S is ~1/3 of MFMAs; VALU hides under PV).
// acc = 64ch x 64q = 64 VGPRs -> no spill (~190 total). Depth-1 K/V prefetch.
// Epilogue: one LDS round combines ks pairs (Ax padded [4][64][68], 70 KB).
// ---------------------------------------------------------------------------
__global__ __launch_bounds__(512, 1) void attn_kernel(
    const bf16_t* __restrict__ Qh, const bf16_t* __restrict__ Kh,
    const bf16_t* __restrict__ Vh, const float* __restrict__ x,
    const float* __restrict__ gamma, float* __restrict__ out)
{
  __shared__ float Ax[4][64][68];   // 69.6 KB: [cg][q][ch-local] (pad 68: 2-way max)
  __shared__ float Lx[64][8];       // 2 KB:   [q][wave]

  const int bi = blockIdx.x;
  const int xcd = bi & 7, slot = bi >> 3;
  const int b  = xcd >> 1;                 // 2 XCDs per batch -> K,V,Q L2-resident
  const int q0 = ((xcd & 1) * 32 + slot) * 64;

  const int t = threadIdx.x, w = t >> 6, lane = t & 63;
  const int l4 = lane >> 4, lm = lane & 15;
  const int cg = w & 3, ks = w >> 2;

  const f32x4 z4 = {0.f, 0.f, 0.f, 0.f};

  // Q fragments (B-operand), held whole kernel
  bf16x8_t qf[4];
#pragma unroll
  for (int rt = 0; rt < 4; ++rt)
    qf[rt] = *(const bf16x8_t*)(Qh + ((size_t)(b * N_ + q0 + rt * 16 + lm)) * D_ + l4 * 8);

  // K base with PERMUTED rows (R17-proven): A-frag row lm covers key kperm+4mt
  const int kperm = 8 * (lm >> 2) + (lm & 3);
  const bf16_t* kbaseP = Kh + ((size_t)(b * N_ + ks * 2048 + kperm)) * D_ + l4 * 8;
  // V base: wave's 64 channels, its own 2048-key half; lane k-elems 8*l4..+7
  const bf16_t* vbase = Vh + ((size_t)(b * C_ + cg * 64 + lm)) * N_ + ks * 2048 + 8 * l4;

  f32x4 acc[4][4];   // [ct][rt] : 64 ch x 64 q, partial over this wave's keys
#pragma unroll
  for (int ct = 0; ct < 4; ++ct)
#pragma unroll
    for (int rt = 0; rt < 4; ++rt) acc[ct][rt] = z4;
  float l_run[4] = {0.f, 0.f, 0.f, 0.f};

  // prologue: K and V fragments for group 0
  bf16x8_t kf[2], kfn[2], vf[4], vfn[4];
#pragma unroll
  for (int mt = 0; mt < 2; ++mt)
    kf[mt] = *(const bf16x8_t*)(kbaseP + (size_t)(4 * mt) * D_);
#pragma unroll
  for (int ct = 0; ct < 4; ++ct)
    vf[ct] = *(const bf16x8_t*)(vbase + (size_t)(ct * 16) * N_);

  // main loop: 64 groups of 32 keys; ZERO barriers, ZERO LDS
#pragma unroll 1
  for (int g = 0; g < 64; ++g) {
    const int ko  = g * 32;
    const int kon = (ko + 32) & 2047;

    // prefetch next K (in flight across S+exp2+PV)
#pragma unroll
    for (int mt = 0; mt < 2; ++mt)
      kfn[mt] = *(const bf16x8_t*)(kbaseP + (size_t)(kon + 4 * mt) * D_);

    // S -> exp2 -> pack (register-resident P, natural key order via kperm)
    bf16x8_t pb[4];
#pragma unroll
    for (int rt = 0; rt < 4; ++rt) {
      const f32x4 S0 = __builtin_amdgcn_mfma_f32_16x16x32_bf16(kf[0], qf[rt], z4, 0, 0, 0);
      const f32x4 S1 = __builtin_amdgcn_mfma_f32_16x16x32_bf16(kf[1], qf[rt], z4, 0, 0, 0);
      float p[8];
#pragma unroll
      for (int r = 0; r < 4; ++r) p[r]     = __builtin_amdgcn_exp2f(S0[r]);
#pragma unroll
      for (int r = 0; r < 4; ++r) p[4 + r] = __builtin_amdgcn_exp2f(S1[r]);
      l_run[rt] += ((p[0] + p[1]) + (p[2] + p[3])) + ((p[4] + p[5]) + (p[6] + p[7]));
      bf16_t tmp[8];
#pragma unroll
      for (int j = 0; j < 8; ++j) tmp[j] = (bf16_t)p[j];
      pb[rt] = *(bf16x8_t*)tmp;
    }

    // prefetch next V (in flight across PV)
#pragma unroll
    for (int ct = 0; ct < 4; ++ct)
      vfn[ct] = *(const bf16x8_t*)(vbase + (size_t)(ct * 16) * N_ + kon);

    // PV: 16 MFMAs, all operands in registers
#pragma unroll
    for (int ct = 0; ct < 4; ++ct)
#pragma unroll
      for (int rt = 0; rt < 4; ++rt)
        acc[ct][rt] = __builtin_amdgcn_mfma_f32_16x16x32_bf16(vf[ct], pb[rt], acc[ct][rt], 0, 0, 0);

#pragma unroll
    for (int mt = 0; mt < 2; ++mt) kf[mt] = kfn[mt];
#pragma unroll
    for (int ct = 0; ct < 4; ++ct) vf[ct] = vfn[ct];
  }

  // ---- l reduce: lane-local -> per-q -> Lx ----
#pragma unroll
  for (int rt = 0; rt < 4; ++rt) {
    l_run[rt] += __shfl_xor(l_run[rt], 16);
    l_run[rt] += __shfl_xor(l_run[rt], 32);
  }
  if (l4 == 0) {
#pragma unroll
    for (int rt = 0; rt < 4; ++rt) Lx[rt * 16 + lm][w] = l_run[rt];
  }

  // ---- ks=1 waves export acc; ks=0 waves combine + store ----
  if (ks == 1) {
#pragma unroll
    for (int ct = 0; ct < 4; ++ct)
#pragma unroll
      for (int rt = 0; rt < 4; ++rt)
        *(f32x4*)&Ax[cg][rt * 16 + lm][ct * 16 + 4 * l4] = acc[ct][rt];
  }
  asm volatile("s_waitcnt lgkmcnt(0)" ::: "memory");
  __builtin_amdgcn_s_barrier();

  if (ks == 0) {
    const float g = gamma[0];
#pragma unroll
    for (int rt = 0; rt < 4; ++rt) {
      const int ql = rt * 16 + lm;
      const float lt = Lx[ql][cg] + Lx[ql][cg + 4];
      const float inv = 1.f / lt;
      const int n = q0 + ql;
#pragma unroll
      for (int ct = 0; ct < 4; ++ct) {
        const f32x4 other = *(const f32x4*)&Ax[cg][ql][ct * 16 + 4 * l4];
#pragma unroll
        for (int r = 0; r < 4; ++r) {
          const int c = cg * 64 + ct * 16 + 4 * l4 + r;
          const size_t idx = ((size_t)(b * C_ + c)) * N_ + n;
          out[idx] = g * ((acc[ct][rt][r] + other[r]) * inv) + x[idx];
        }
      }
    }
  }
}

extern "C" void kernel_launch(void* const* d_in, const int* in_sizes, int n_in,
                              void* d_out, int out_size, void* d_ws, size_t ws_size,
                              hipStream_t stream) {
  const float* x     = (const float*)d_in[0];
  const float* wq    = (const float*)d_in[1];
  const float* bq    = (const float*)d_in[2];
  const float* wk    = (const float*)d_in[3];
  const float* bk    = (const float*)d_in[4];
  const float* wv    = (const float*)d_in[5];
  const float* bv    = (const float*)d_in[6];
  const float* gamma = (const float*)d_in[7];
  float* out = (float*)d_out;

  bf16_t* Qh = (bf16_t*)d_ws;
  bf16_t* Kh = Qh + (size_t)B_ * N_ * D_;
  bf16_t* Vh = Kh + (size_t)B_ * N_ * D_;
  bf16_t* Wb = Vh + (size_t)B_ * C_ * N_;

  cast_w_kernel<<<320, 256, 0, stream>>>(wq, wk, wv, Wb);
  proj_kernel<<<256, 256, 0, stream>>>(x, Wb, bq, bk, bv, Qh, Kh, Vh);
  attn_kernel<<<256, 512, 0, stream>>>(Qh, Kh, Vh, x, gamma, out);
}